// Round 3
// baseline (112.234 us; speedup 1.0000x reference)
//
#include <hip/hip_runtime.h>
#include <hip/hip_bf16.h>

typedef __bf16 bf16;
typedef __attribute__((ext_vector_type(4))) __bf16 bf16x4;
typedef __attribute__((ext_vector_type(8))) __bf16 bf16x8;
typedef __attribute__((ext_vector_type(4))) float f32x4;

#define D_MODEL 1024
#define DK 128
#define LSEQ 2048
#define NQT 128                       // 16-row q-tiles per batch
#define NB 4
// 1/sqrt(128) * log2(e): softmax runs in exp2 domain end-to-end
#define SCALE2 (0.08838834764831845f * 1.4426950408889634f)

// ---------------------------------------------------------------------------
// Kernel 0: transpose + bf16-convert weights. W[1024][128] f32 -> Wt[3][128][1024]
// ---------------------------------------------------------------------------
__global__ __launch_bounds__(256) void wt_kernel(
    const float* __restrict__ Wq, const float* __restrict__ Wk,
    const float* __restrict__ Wv, bf16* __restrict__ Wt)
{
    __shared__ bf16 tile[64][72];
    const float* W = (blockIdx.z == 0) ? Wq : (blockIdx.z == 1) ? Wk : Wv;
    int k0 = blockIdx.x * 64;
    int n0 = blockIdx.y * 64;
    int t  = threadIdx.x;
    #pragma unroll
    for (int i = 0; i < 16; ++i) {
        int idx = t + i * 256;
        int r = idx >> 6, c = idx & 63;
        tile[c][r] = (bf16)W[(size_t)(k0 + r) * DK + n0 + c];
    }
    __syncthreads();
    bf16* out = Wt + (size_t)blockIdx.z * DK * D_MODEL;
    #pragma unroll
    for (int i = 0; i < 16; ++i) {
        int idx = t + i * 256;
        int rr = idx >> 6, cc = idx & 63;
        out[(size_t)(n0 + rr) * D_MODEL + k0 + cc] = tile[rr][cc];
    }
}

// ---------------------------------------------------------------------------
// Kernel 1: QKV projection GEMM (bf16 MFMA). M-tile 64 (384 blocks for CU
// coverage), N=128, BK=64. 4 waves x 16 rows. Q pre-scaled by log2e/sqrt(dk).
// ---------------------------------------------------------------------------
__global__ __launch_bounds__(256) void proj_kernel(
    const float* __restrict__ X, const bf16* __restrict__ Wt,
    bf16* __restrict__ Qs, bf16* __restrict__ Kb, bf16* __restrict__ Vt)
{
    __shared__ bf16 Xs[64][72];
    __shared__ bf16 Ws[128][72];
    int mt = blockIdx.x, mat = blockIdx.y;
    const bf16* W = Wt + (size_t)mat * DK * D_MODEL;
    int t = threadIdx.x;
    int wave = t >> 6, lane = t & 63;
    int lq = lane & 15, g = lane >> 4;
    int row0 = mt * 64;

    f32x4 acc[8];
    #pragma unroll
    for (int n = 0; n < 8; ++n) acc[n] = f32x4{0.f, 0.f, 0.f, 0.f};

    for (int k0 = 0; k0 < D_MODEL; k0 += 64) {
        __syncthreads();
        // stage X tile 64x64 f32 -> bf16
        #pragma unroll
        for (int i = 0; i < 4; ++i) {
            int idx = t + i * 256;
            int r = idx >> 4, c4 = idx & 15;
            f32x4 v = *reinterpret_cast<const f32x4*>(
                &X[(size_t)(row0 + r) * D_MODEL + k0 + c4 * 4]);
            bf16x4 h; h[0]=(bf16)v[0]; h[1]=(bf16)v[1]; h[2]=(bf16)v[2]; h[3]=(bf16)v[3];
            *reinterpret_cast<bf16x4*>(&Xs[r][c4 * 4]) = h;
        }
        // stage Wt tile 128x64 bf16
        #pragma unroll
        for (int i = 0; i < 4; ++i) {
            int idx = t + i * 256;
            int r = idx >> 3, c8 = idx & 7;
            *reinterpret_cast<bf16x8*>(&Ws[r][c8 * 8]) =
                *reinterpret_cast<const bf16x8*>(&W[(size_t)r * D_MODEL + k0 + c8 * 8]);
        }
        __syncthreads();
        #pragma unroll
        for (int kk = 0; kk < 2; ++kk) {
            bf16x8 a = *reinterpret_cast<const bf16x8*>(&Xs[wave * 16 + lq][kk * 32 + g * 8]);
            #pragma unroll
            for (int nt = 0; nt < 8; ++nt) {
                bf16x8 bfr = *reinterpret_cast<const bf16x8*>(&Ws[nt * 16 + lq][kk * 32 + g * 8]);
                acc[nt] = __builtin_amdgcn_mfma_f32_16x16x32_bf16(a, bfr, acc[nt], 0, 0, 0);
            }
        }
    }
    int rbase = row0 + wave * 16 + g * 4;
    if (mat == 0) {
        #pragma unroll
        for (int nt = 0; nt < 8; ++nt)
            #pragma unroll
            for (int r = 0; r < 4; ++r)
                Qs[(size_t)(rbase + r) * DK + nt * 16 + lq] = (bf16)(acc[nt][r] * SCALE2);
    } else if (mat == 1) {
        #pragma unroll
        for (int nt = 0; nt < 8; ++nt)
            #pragma unroll
            for (int r = 0; r < 4; ++r)
                Kb[(size_t)(rbase + r) * DK + nt * 16 + lq] = (bf16)acc[nt][r];
    } else {
        int bb  = rbase >> 11;
        int kv0 = rbase & 2047;
        #pragma unroll
        for (int nt = 0; nt < 8; ++nt) {
            bf16x4 h;
            h[0]=(bf16)acc[nt][0]; h[1]=(bf16)acc[nt][1];
            h[2]=(bf16)acc[nt][2]; h[3]=(bf16)acc[nt][3];
            *reinterpret_cast<bf16x4*>(
                &Vt[((size_t)bb * DK + nt * 16 + lq) * LSEQ + kv0]) = h;
        }
    }
}

// ---------------------------------------------------------------------------
// Kernel 2: split-KV causal flash attention. 256-thr blocks, 4 waves, each
// wave owns 16 q-rows (no inter-wave sync; P round-trip is wave-local).
// kv-tile = 64 wide. S=8 path uses XCD-aware decode: batch = xcd>>1 so each
// XCD's K/V working set is one batch (L2-fit), with complementary (q,31-q)
// pairing per CU for causal balance.
// ---------------------------------------------------------------------------
__global__ __launch_bounds__(256, 4) void attn_kernel(
    const bf16* __restrict__ Qs, const bf16* __restrict__ Kb,
    const bf16* __restrict__ Vt, float* __restrict__ Zp,
    float* __restrict__ Mp, float* __restrict__ Lp,
    float* __restrict__ Out, int S, int direct)
{
    __shared__ bf16 P[4][16][72];
    int bid = blockIdx.x;
    int b, qblk, s;
    if (S == 8) {
        int xcd = bid & 7, n = bid >> 3;          // n in [0,128)
        b = xcd >> 1;
        int half = n >> 6, nn = n & 63;
        int qraw = nn & 31;
        qblk = half ? (31 - qraw) : qraw;
        s = (nn >> 5) | (half << 1) | ((xcd & 1) << 2);
    } else {
        b = bid / (S * 32);
        int rem = bid % (S * 32);
        qblk = rem % 32;
        s = rem / 32;
    }
    int wave = threadIdx.x >> 6, lane = threadIdx.x & 63;
    int lq = lane & 15, g = lane >> 4;
    int qw16 = qblk * 4 + wave;          // global 16-row q-tile id, 0..127
    int base = qw16 * 16;
    int qg = base + lq;

    int nt  = (base + 79) >> 6;          // 64-wide kv tiles needed by this wave
    int cpt = (nt + S - 1) / S;
    int t0  = s * cpt;
    int t1  = min(t0 + cpt, nt);

    const bf16* Qrow = Qs + ((size_t)b * LSEQ + qg) * DK;
    bf16x8 qf[4];
    #pragma unroll
    for (int ks = 0; ks < 4; ++ks)
        qf[ks] = *reinterpret_cast<const bf16x8*>(&Qrow[ks * 32 + g * 8]);

    f32x4 z[8];
    #pragma unroll
    for (int i = 0; i < 8; ++i) z[i] = f32x4{0.f, 0.f, 0.f, 0.f};
    float mrun = -3.0e38f, lrun = 0.f;

    const bf16* Kbase = Kb + (size_t)b * LSEQ * DK;
    const bf16* Vbase = Vt + (size_t)b * DK * LSEQ;
    bf16 (*Pw)[72] = P[wave];

    for (int ti = t0; ti < t1; ++ti) {
        int kvb = ti * 64;
        f32x4 sc[4];
        #pragma unroll
        for (int jj = 0; jj < 4; ++jj) sc[jj] = f32x4{0.f, 0.f, 0.f, 0.f};
        const bf16* Kt = Kbase + (size_t)(kvb + lq) * DK + g * 8;
        #pragma unroll
        for (int jj = 0; jj < 4; ++jj) {
            #pragma unroll
            for (int ks = 0; ks < 4; ++ks) {
                bf16x8 a = *reinterpret_cast<const bf16x8*>(Kt + (size_t)jj * 16 * DK + ks * 32);
                sc[jj] = __builtin_amdgcn_mfma_f32_16x16x32_bf16(a, qf[ks], sc[jj], 0, 0, 0);
            }
        }
        float sv[16];
        if (ti == nt - 1) {              // only the wave's last tile straddles
            #pragma unroll
            for (int jj = 0; jj < 4; ++jj)
                #pragma unroll
                for (int r = 0; r < 4; ++r) {
                    int kv0 = kvb + jj * 16 + g * 4 + r;
                    sv[jj * 4 + r] = (kv0 <= qg) ? sc[jj][r] : -3.0e38f;
                }
        } else {
            #pragma unroll
            for (int jj = 0; jj < 4; ++jj)
                #pragma unroll
                for (int r = 0; r < 4; ++r) sv[jj * 4 + r] = sc[jj][r];
        }
        float mt = sv[0];
        #pragma unroll
        for (int i = 1; i < 16; ++i) mt = fmaxf(mt, sv[i]);
        mt = fmaxf(mt, __shfl_xor(mt, 16));
        mt = fmaxf(mt, __shfl_xor(mt, 32));
        if (!__all(mt <= mrun)) {
            float mnew  = fmaxf(mrun, mt);
            float alpha = exp2f(mrun - mnew);
            lrun *= alpha;
            #pragma unroll
            for (int i = 0; i < 8; ++i) {
                z[i][0] *= alpha; z[i][1] *= alpha; z[i][2] *= alpha; z[i][3] *= alpha;
            }
            mrun = mnew;
        }
        float psum = 0.f;
        #pragma unroll
        for (int jj = 0; jj < 4; ++jj) {
            bf16x4 pb;
            #pragma unroll
            for (int r = 0; r < 4; ++r) {
                float e = exp2f(sv[jj * 4 + r] - mrun);
                psum += e;
                pb[r] = (bf16)e;
            }
            *reinterpret_cast<bf16x4*>(&Pw[lq][jj * 16 + g * 4]) = pb;
        }
        psum += __shfl_xor(psum, 16);
        psum += __shfl_xor(psum, 32);
        lrun += psum;
        #pragma unroll
        for (int sl = 0; sl < 2; ++sl) {
            bf16x8 pf = *reinterpret_cast<const bf16x8*>(&Pw[lq][sl * 32 + g * 8]);
            #pragma unroll
            for (int dt = 0; dt < 8; ++dt) {
                bf16x8 av = *reinterpret_cast<const bf16x8*>(
                    &Vbase[(size_t)(dt * 16 + lq) * LSEQ + kvb + sl * 32 + g * 8]);
                z[dt] = __builtin_amdgcn_mfma_f32_16x16x32_bf16(av, pf, z[dt], 0, 0, 0);
            }
        }
    }

    if (direct) {
        float inv = 1.f / lrun;
        float* orow = Out + ((size_t)b * LSEQ + qg) * DK;
        #pragma unroll
        for (int dt = 0; dt < 8; ++dt) {
            f32x4 v;
            v[0]=z[dt][0]*inv; v[1]=z[dt][1]*inv; v[2]=z[dt][2]*inv; v[3]=z[dt][3]*inv;
            *reinterpret_cast<f32x4*>(&orow[dt * 16 + g * 4]) = v;
        }
    } else {
        size_t T = ((size_t)(b * NQT + qw16) * S + s);
        float* zp = Zp + T * (16 * 128);
        #pragma unroll
        for (int dt = 0; dt < 8; ++dt)
            *reinterpret_cast<f32x4*>(&zp[lq * 128 + dt * 16 + g * 4]) = z[dt];
        if (g == 0) {
            Mp[T * 16 + lq] = mrun;
            Lp[T * 16 + lq] = lrun;
        }
    }
}

// ---------------------------------------------------------------------------
// Kernel 3: merge split-KV partials. One block per (qt16, b), 256 threads.
// ---------------------------------------------------------------------------
__global__ __launch_bounds__(256) void combine_kernel(
    const float* __restrict__ Zp, const float* __restrict__ Mp,
    const float* __restrict__ Lp, float* __restrict__ Out, int S)
{
    int qt = blockIdx.x, b = blockIdx.y;
    int t  = threadIdx.x;
    int r  = t >> 4;
    int d0 = (t & 15) * 8;
    size_t Tbase = (size_t)(b * NQT + qt) * S;

    float m = -3.0e38f;
    for (int s = 0; s < S; ++s)
        m = fmaxf(m, Mp[(Tbase + s) * 16 + r]);

    float L = 0.f;
    f32x4 a0 = {0.f,0.f,0.f,0.f}, a1 = {0.f,0.f,0.f,0.f};
    for (int s = 0; s < S; ++s) {
        float w = exp2f(Mp[(Tbase + s) * 16 + r] - m);
        L += w * Lp[(Tbase + s) * 16 + r];
        const float* zp = Zp + (Tbase + s) * (16 * 128) + r * 128 + d0;
        f32x4 v0 = *reinterpret_cast<const f32x4*>(&zp[0]);
        f32x4 v1 = *reinterpret_cast<const f32x4*>(&zp[4]);
        a0[0]+=w*v0[0]; a0[1]+=w*v0[1]; a0[2]+=w*v0[2]; a0[3]+=w*v0[3];
        a1[0]+=w*v1[0]; a1[1]+=w*v1[1]; a1[2]+=w*v1[2]; a1[3]+=w*v1[3];
    }
    float inv = 1.f / L;
    float* orow = Out + ((size_t)b * LSEQ + qt * 16 + r) * DK + d0;
    f32x4 o0, o1;
    o0[0]=a0[0]*inv; o0[1]=a0[1]*inv; o0[2]=a0[2]*inv; o0[3]=a0[3]*inv;
    o1[0]=a1[0]*inv; o1[1]=a1[1]*inv; o1[2]=a1[2]*inv; o1[3]=a1[3]*inv;
    *reinterpret_cast<f32x4*>(&orow[0]) = o0;
    *reinterpret_cast<f32x4*>(&orow[4]) = o1;
}

// ---------------------------------------------------------------------------
extern "C" void kernel_launch(void* const* d_in, const int* in_sizes, int n_in,
                              void* d_out, int out_size, void* d_ws, size_t ws_size,
                              hipStream_t stream)
{
    const float* X  = (const float*)d_in[0];
    const float* Wq = (const float*)d_in[1];
    const float* Wk = (const float*)d_in[2];
    const float* Wv = (const float*)d_in[3];
    float* Out = (float*)d_out;

    char* ws = (char*)d_ws;
    bf16* Wt = (bf16*)(ws);
    bf16* Qs = (bf16*)(ws + (size_t)1 * (1 << 20));
    bf16* Kb = (bf16*)(ws + (size_t)3 * (1 << 20));
    bf16* Vt = (bf16*)(ws + (size_t)5 * (1 << 20));
    size_t base = (size_t)7 << 20;

    auto need = [](int S) -> size_t {
        return ((size_t)7 << 20) + (size_t)S * ((size_t)NB * NQT * 16 * 128 * 4)
                                 + (size_t)S * 2 * ((size_t)NB * NQT * 16 * 4);
    };
    int S = 1;
    if      (ws_size >= need(8)) S = 8;
    else if (ws_size >= need(4)) S = 4;
    else if (ws_size >= need(2)) S = 2;

    float* Zp = (float*)(ws + base);
    float* Mp = (float*)(ws + base + (size_t)S * NB * NQT * 16 * 128 * 4);
    float* Lp = (float*)(ws + base + (size_t)S * NB * NQT * 16 * 128 * 4
                                   + (size_t)S * NB * NQT * 16 * 4);

    hipLaunchKernelGGL(wt_kernel,   dim3(16, 2, 3), dim3(256), 0, stream, Wq, Wk, Wv, Wt);
    hipLaunchKernelGGL(proj_kernel, dim3(128, 3),   dim3(256), 0, stream, X, Wt, Qs, Kb, Vt);
    hipLaunchKernelGGL(attn_kernel, dim3(S * 32 * NB), dim3(256), 0, stream,
                       Qs, Kb, Vt, Zp, Mp, Lp, Out, S, (S == 1) ? 1 : 0);
    if (S > 1)
        hipLaunchKernelGGL(combine_kernel, dim3(NQT, NB), dim3(256), 0, stream,
                           Zp, Mp, Lp, Out, S);
}

// Round 4
// 58.806 us; speedup vs baseline: 1.9086x; 1.9086x over previous
//
#include <hip/hip_runtime.h>
#include <hip/hip_bf16.h>

typedef __bf16 bf16;
typedef __attribute__((ext_vector_type(4))) __bf16 bf16x4;
typedef __attribute__((ext_vector_type(8))) __bf16 bf16x8;
typedef __attribute__((ext_vector_type(4))) float f32x4;

#define D_MODEL 1024
#define DK 128
#define LSEQ 2048
#define NQT 128
#define NB 4
// 1/sqrt(128) * log2(e): softmax runs in exp2 domain end-to-end
#define SCALE2 (0.08838834764831845f * 1.4426950408889634f)

// ---------------------------------------------------------------------------
// Kernel A: X f32 -> Xb bf16 (pure bandwidth pass)
// ---------------------------------------------------------------------------
__global__ __launch_bounds__(256) void xb_kernel(
    const float* __restrict__ X, bf16* __restrict__ Xb)
{
    size_t i = ((size_t)blockIdx.x * 256 + threadIdx.x) * 8;
    f32x4 a = *reinterpret_cast<const f32x4*>(&X[i]);
    f32x4 b = *reinterpret_cast<const f32x4*>(&X[i + 4]);
    bf16x8 h;
    h[0]=(bf16)a[0]; h[1]=(bf16)a[1]; h[2]=(bf16)a[2]; h[3]=(bf16)a[3];
    h[4]=(bf16)b[0]; h[5]=(bf16)b[1]; h[6]=(bf16)b[2]; h[7]=(bf16)b[3];
    *reinterpret_cast<bf16x8*>(&Xb[i]) = h;
}

// ---------------------------------------------------------------------------
// Kernel 0: transpose + bf16-convert weights. W[1024][128] f32 -> Wt[3][128][1024]
// ---------------------------------------------------------------------------
__global__ __launch_bounds__(256) void wt_kernel(
    const float* __restrict__ Wq, const float* __restrict__ Wk,
    const float* __restrict__ Wv, bf16* __restrict__ Wt)
{
    __shared__ bf16 tile[64][72];
    const float* W = (blockIdx.z == 0) ? Wq : (blockIdx.z == 1) ? Wk : Wv;
    int k0 = blockIdx.x * 64;
    int n0 = blockIdx.y * 64;
    int t  = threadIdx.x;
    #pragma unroll
    for (int i = 0; i < 16; ++i) {
        int idx = t + i * 256;
        int r = idx >> 6, c = idx & 63;
        tile[c][r] = (bf16)W[(size_t)(k0 + r) * DK + n0 + c];
    }
    __syncthreads();
    bf16* out = Wt + (size_t)blockIdx.z * DK * D_MODEL;
    #pragma unroll
    for (int i = 0; i < 16; ++i) {
        int idx = t + i * 256;
        int rr = idx >> 6, cc = idx & 63;
        out[(size_t)(n0 + rr) * D_MODEL + k0 + cc] = tile[rr][cc];
    }
}

// ---------------------------------------------------------------------------
// Kernel 1: QKV projection GEMM. Xb bf16 [8192][1024] x Wt[mat][128][1024].
// M-tile 64, BK 64, 4 waves; wave = 64 rows x 32 cols (acc[4][2]).
// Reg-staged double-buffer: loads for step k+1 issue during compute of step k.
// ---------------------------------------------------------------------------
__global__ __launch_bounds__(256) void proj_kernel(
    const bf16* __restrict__ Xb, const bf16* __restrict__ Wt,
    bf16* __restrict__ Qs, bf16* __restrict__ Kb, bf16* __restrict__ Vt)
{
    __shared__ bf16 Xs[64][72];
    __shared__ bf16 Ws[128][72];
    int mt = blockIdx.x, mat = blockIdx.y;
    const bf16* W = Wt + (size_t)mat * DK * D_MODEL;
    int t = threadIdx.x;
    int wave = t >> 6, lane = t & 63;
    int lq = lane & 15, g = lane >> 4;
    int row0 = mt * 64;

    f32x4 acc[4][2];
    #pragma unroll
    for (int m = 0; m < 4; ++m)
        #pragma unroll
        for (int n = 0; n < 2; ++n) acc[m][n] = f32x4{0.f, 0.f, 0.f, 0.f};

    bf16x8 rx[2], rw[4];
    auto LOADR = [&](int k0) {
        #pragma unroll
        for (int i = 0; i < 2; ++i) {
            int u = t + i * 256, r = u >> 3, c = u & 7;
            rx[i] = *reinterpret_cast<const bf16x8*>(
                &Xb[(size_t)(row0 + r) * D_MODEL + k0 + c * 8]);
        }
        #pragma unroll
        for (int i = 0; i < 4; ++i) {
            int u = t + i * 256, r = u >> 3, c = u & 7;
            rw[i] = *reinterpret_cast<const bf16x8*>(
                &W[(size_t)r * D_MODEL + k0 + c * 8]);
        }
    };
    auto STORER = [&]() {
        #pragma unroll
        for (int i = 0; i < 2; ++i) {
            int u = t + i * 256, r = u >> 3, c = u & 7;
            *reinterpret_cast<bf16x8*>(&Xs[r][c * 8]) = rx[i];
        }
        #pragma unroll
        for (int i = 0; i < 4; ++i) {
            int u = t + i * 256, r = u >> 3, c = u & 7;
            *reinterpret_cast<bf16x8*>(&Ws[r][c * 8]) = rw[i];
        }
    };

    LOADR(0);
    for (int ks = 0; ks < 16; ++ks) {
        __syncthreads();               // all waves done reading previous LDS
        STORER();
        if (ks + 1 < 16) LOADR((ks + 1) * 64);   // in flight during compute
        __syncthreads();
        #pragma unroll
        for (int kk = 0; kk < 2; ++kk) {
            bf16x8 a[4];
            #pragma unroll
            for (int mr = 0; mr < 4; ++mr)
                a[mr] = *reinterpret_cast<const bf16x8*>(&Xs[mr * 16 + lq][kk * 32 + g * 8]);
            #pragma unroll
            for (int n = 0; n < 2; ++n) {
                bf16x8 bfr = *reinterpret_cast<const bf16x8*>(
                    &Ws[wave * 32 + n * 16 + lq][kk * 32 + g * 8]);
                #pragma unroll
                for (int mr = 0; mr < 4; ++mr)
                    acc[mr][n] = __builtin_amdgcn_mfma_f32_16x16x32_bf16(a[mr], bfr, acc[mr][n], 0, 0, 0);
            }
        }
    }
    // epilogue: out row = row0 + mr*16 + g*4 + r ; col = wave*32 + n*16 + lq
    #pragma unroll
    for (int mr = 0; mr < 4; ++mr) {
        int orow = row0 + mr * 16 + g * 4;
        #pragma unroll
        for (int n = 0; n < 2; ++n) {
            int col = wave * 32 + n * 16 + lq;
            if (mat == 0) {
                #pragma unroll
                for (int r = 0; r < 4; ++r)
                    Qs[(size_t)(orow + r) * DK + col] = (bf16)(acc[mr][n][r] * SCALE2);
            } else if (mat == 1) {
                #pragma unroll
                for (int r = 0; r < 4; ++r)
                    Kb[(size_t)(orow + r) * DK + col] = (bf16)acc[mr][n][r];
            } else {
                int bb  = orow >> 11;
                int kv0 = orow & 2047;
                bf16x4 h;
                h[0]=(bf16)acc[mr][n][0]; h[1]=(bf16)acc[mr][n][1];
                h[2]=(bf16)acc[mr][n][2]; h[3]=(bf16)acc[mr][n][3];
                *reinterpret_cast<bf16x4*>(
                    &Vt[((size_t)bb * DK + col) * LSEQ + kv0]) = h;
            }
        }
    }
}

// ---------------------------------------------------------------------------
// Kernel 2: split-KV causal flash attention, block-shared K/V LDS staging.
// Block = 4 waves = 64 contiguous q-rows; all waves share the SAME kv range
// (nt = qblk+1 for every wave), so K[64][128] and V[128][64] are staged once
// per block per tile, reg-prefetched (T14) one tile ahead.
// ---------------------------------------------------------------------------
__global__ __launch_bounds__(256, 2) void attn_kernel(
    const bf16* __restrict__ Qs, const bf16* __restrict__ Kb,
    const bf16* __restrict__ Vt, float* __restrict__ Zp,
    float* __restrict__ Mp, float* __restrict__ Lp,
    float* __restrict__ Out, int S, int direct)
{
    __shared__ bf16 Ks[64][136];
    __shared__ bf16 Vs[128][72];
    __shared__ bf16 P[4][16][72];
    int bid = blockIdx.x;
    int b, qblk, s;
    if (S == 4) {
        int xcd = bid & 7, n = bid >> 3;      // n in [0,64)
        b = xcd >> 1;                         // XCD-pinned batch (L2 locality)
        int half = n >> 5, qraw = n & 31;
        qblk = half ? (31 - qraw) : qraw;     // complementary pairing
        s = ((xcd & 1) << 1) | half;
    } else {
        b = bid / (S * 32);
        int rem = bid % (S * 32);
        qblk = rem & 31;
        s = rem >> 5;
    }
    int t = threadIdx.x;
    int wave = t >> 6, lane = t & 63;
    int lq = lane & 15, g = lane >> 4;
    int qw16 = qblk * 4 + wave;
    int qg = qw16 * 16 + lq;

    int nt  = qblk + 1;                  // identical for all 4 waves
    int cpt = (nt + S - 1) / S;
    int t0  = s * cpt;
    int t1  = min(t0 + cpt, nt);

    const bf16* Kbase = Kb + (size_t)b * LSEQ * DK;
    const bf16* Vbase = Vt + (size_t)b * DK * LSEQ;

    const bf16* Qrow = Qs + ((size_t)b * LSEQ + qg) * DK;
    bf16x8 qf[4];
    #pragma unroll
    for (int ks = 0; ks < 4; ++ks)
        qf[ks] = *reinterpret_cast<const bf16x8*>(&Qrow[ks * 32 + g * 8]);

    f32x4 z[8];
    #pragma unroll
    for (int i = 0; i < 8; ++i) z[i] = f32x4{0.f, 0.f, 0.f, 0.f};
    float mrun = -3.0e38f, lrun = 0.f;

    bf16x8 kreg[4], vreg[4];
    auto LOADKV = [&](int kvb) {
        #pragma unroll
        for (int i = 0; i < 4; ++i) {        // K: 64 rows x 16 chunks
            int u = t + i * 256, r = u >> 4, c = u & 15;
            kreg[i] = *reinterpret_cast<const bf16x8*>(
                &Kbase[(size_t)(kvb + r) * DK + c * 8]);
        }
        #pragma unroll
        for (int i = 0; i < 4; ++i) {        // V: 128 rows x 8 chunks
            int u = t + i * 256, d = u >> 3, c = u & 7;
            vreg[i] = *reinterpret_cast<const bf16x8*>(
                &Vbase[(size_t)d * LSEQ + kvb + c * 8]);
        }
    };
    auto STOREKV = [&]() {
        #pragma unroll
        for (int i = 0; i < 4; ++i) {
            int u = t + i * 256, r = u >> 4, c = u & 15;
            *reinterpret_cast<bf16x8*>(&Ks[r][c * 8]) = kreg[i];
        }
        #pragma unroll
        for (int i = 0; i < 4; ++i) {
            int u = t + i * 256, d = u >> 3, c = u & 7;
            *reinterpret_cast<bf16x8*>(&Vs[d][c * 8]) = vreg[i];
        }
    };

    if (t0 < t1) {                       // block-uniform
        LOADKV(t0 * 64);
        for (int ti = t0; ti < t1; ++ti) {
            int kvb = ti * 64;
            __syncthreads();             // prev tile's readers done
            STOREKV();
            if (ti + 1 < t1) LOADKV((ti + 1) * 64);   // hide under compute
            __syncthreads();             // LDS tile visible

            f32x4 sc[4];
            #pragma unroll
            for (int jj = 0; jj < 4; ++jj) sc[jj] = f32x4{0.f, 0.f, 0.f, 0.f};
            #pragma unroll
            for (int jj = 0; jj < 4; ++jj)
                #pragma unroll
                for (int ks = 0; ks < 4; ++ks) {
                    bf16x8 a = *reinterpret_cast<const bf16x8*>(
                        &Ks[jj * 16 + lq][ks * 32 + g * 8]);
                    sc[jj] = __builtin_amdgcn_mfma_f32_16x16x32_bf16(a, qf[ks], sc[jj], 0, 0, 0);
                }

            float sv[16];
            if (ti == nt - 1) {          // only the diagonal tile masks
                #pragma unroll
                for (int jj = 0; jj < 4; ++jj)
                    #pragma unroll
                    for (int r = 0; r < 4; ++r) {
                        int kv0 = kvb + jj * 16 + g * 4 + r;
                        sv[jj * 4 + r] = (kv0 <= qg) ? sc[jj][r] : -3.0e38f;
                    }
            } else {
                #pragma unroll
                for (int jj = 0; jj < 4; ++jj)
                    #pragma unroll
                    for (int r = 0; r < 4; ++r) sv[jj * 4 + r] = sc[jj][r];
            }
            float mt = sv[0];
            #pragma unroll
            for (int i = 1; i < 16; ++i) mt = fmaxf(mt, sv[i]);
            mt = fmaxf(mt, __shfl_xor(mt, 16));
            mt = fmaxf(mt, __shfl_xor(mt, 32));
            if (!__all(mt <= mrun)) {
                float mnew  = fmaxf(mrun, mt);
                float alpha = exp2f(mrun - mnew);
                lrun *= alpha;
                #pragma unroll
                for (int i = 0; i < 8; ++i) {
                    z[i][0] *= alpha; z[i][1] *= alpha; z[i][2] *= alpha; z[i][3] *= alpha;
                }
                mrun = mnew;
            }
            float psum = 0.f;
            #pragma unroll
            for (int jj = 0; jj < 4; ++jj) {
                bf16x4 pb;
                #pragma unroll
                for (int r = 0; r < 4; ++r) {
                    float e = exp2f(sv[jj * 4 + r] - mrun);
                    psum += e;
                    pb[r] = (bf16)e;
                }
                *reinterpret_cast<bf16x4*>(&P[wave][lq][jj * 16 + g * 4]) = pb;
            }
            psum += __shfl_xor(psum, 16);
            psum += __shfl_xor(psum, 32);
            lrun += psum;
            #pragma unroll
            for (int sl = 0; sl < 2; ++sl) {
                bf16x8 pf = *reinterpret_cast<const bf16x8*>(&P[wave][lq][sl * 32 + g * 8]);
                #pragma unroll
                for (int dt = 0; dt < 8; ++dt) {
                    bf16x8 av = *reinterpret_cast<const bf16x8*>(
                        &Vs[dt * 16 + lq][sl * 32 + g * 8]);
                    z[dt] = __builtin_amdgcn_mfma_f32_16x16x32_bf16(av, pf, z[dt], 0, 0, 0);
                }
            }
        }
    }

    if (direct) {
        float inv = 1.f / lrun;
        float* orow = Out + ((size_t)b * LSEQ + qg) * DK;
        #pragma unroll
        for (int dt = 0; dt < 8; ++dt) {
            f32x4 v;
            v[0]=z[dt][0]*inv; v[1]=z[dt][1]*inv; v[2]=z[dt][2]*inv; v[3]=z[dt][3]*inv;
            *reinterpret_cast<f32x4*>(&orow[dt * 16 + g * 4]) = v;
        }
    } else {
        size_t T = ((size_t)(b * NQT + qw16) * S + s);
        float* zp = Zp + T * (16 * 128);
        #pragma unroll
        for (int dt = 0; dt < 8; ++dt)
            *reinterpret_cast<f32x4*>(&zp[lq * 128 + dt * 16 + g * 4]) = z[dt];
        if (g == 0) {
            Mp[T * 16 + lq] = mrun;
            Lp[T * 16 + lq] = lrun;
        }
    }
}

// ---------------------------------------------------------------------------
// Kernel 3: merge split-KV partials. One block per (qt16, b), 256 threads.
// ---------------------------------------------------------------------------
__global__ __launch_bounds__(256) void combine_kernel(
    const float* __restrict__ Zp, const float* __restrict__ Mp,
    const float* __restrict__ Lp, float* __restrict__ Out, int S)
{
    int qt = blockIdx.x, b = blockIdx.y;
    int t  = threadIdx.x;
    int r  = t >> 4;
    int d0 = (t & 15) * 8;
    size_t Tbase = (size_t)(b * NQT + qt) * S;

    float m = -3.0e38f;
    for (int s = 0; s < S; ++s)
        m = fmaxf(m, Mp[(Tbase + s) * 16 + r]);

    float L = 0.f;
    f32x4 a0 = {0.f,0.f,0.f,0.f}, a1 = {0.f,0.f,0.f,0.f};
    for (int s = 0; s < S; ++s) {
        float w = exp2f(Mp[(Tbase + s) * 16 + r] - m);
        L += w * Lp[(Tbase + s) * 16 + r];
        const float* zp = Zp + (Tbase + s) * (16 * 128) + r * 128 + d0;
        f32x4 v0 = *reinterpret_cast<const f32x4*>(&zp[0]);
        f32x4 v1 = *reinterpret_cast<const f32x4*>(&zp[4]);
        a0[0]+=w*v0[0]; a0[1]+=w*v0[1]; a0[2]+=w*v0[2]; a0[3]+=w*v0[3];
        a1[0]+=w*v1[0]; a1[1]+=w*v1[1]; a1[2]+=w*v1[2]; a1[3]+=w*v1[3];
    }
    float inv = 1.f / L;
    float* orow = Out + ((size_t)b * LSEQ + qt * 16 + r) * DK + d0;
    f32x4 o0, o1;
    o0[0]=a0[0]*inv; o0[1]=a0[1]*inv; o0[2]=a0[2]*inv; o0[3]=a0[3]*inv;
    o1[0]=a1[0]*inv; o1[1]=a1[1]*inv; o1[2]=a1[2]*inv; o1[3]=a1[3]*inv;
    *reinterpret_cast<f32x4*>(&orow[0]) = o0;
    *reinterpret_cast<f32x4*>(&orow[4]) = o1;
}

// ---------------------------------------------------------------------------
extern "C" void kernel_launch(void* const* d_in, const int* in_sizes, int n_in,
                              void* d_out, int out_size, void* d_ws, size_t ws_size,
                              hipStream_t stream)
{
    const float* X  = (const float*)d_in[0];
    const float* Wq = (const float*)d_in[1];
    const float* Wk = (const float*)d_in[2];
    const float* Wv = (const float*)d_in[3];
    float* Out = (float*)d_out;

    char* ws = (char*)d_ws;
    // layout: Wt @0 (768KB) ; Xb @1MB (16MB) ; Qs @17MB ; Kb @19MB ; Vt @21MB ;
    //         partials @23MB
    bf16* Wt = (bf16*)(ws);
    bf16* Xb = (bf16*)(ws + ((size_t)1 << 20));
    bf16* Qs = (bf16*)(ws + ((size_t)17 << 20));
    bf16* Kb = (bf16*)(ws + ((size_t)19 << 20));
    bf16* Vt = (bf16*)(ws + ((size_t)21 << 20));
    size_t base = (size_t)23 << 20;

    auto need = [](int S) -> size_t {
        return ((size_t)23 << 20) + (size_t)S * ((size_t)NB * NQT * 16 * 128 * 4)
                                  + (size_t)S * 2 * ((size_t)NB * NQT * 16 * 4);
    };
    int S = 1;
    if      (ws_size >= need(4)) S = 4;
    else if (ws_size >= need(2)) S = 2;

    float* Zp = (float*)(ws + base);
    float* Mp = (float*)(ws + base + (size_t)S * NB * NQT * 16 * 128 * 4);
    float* Lp = (float*)(ws + base + (size_t)S * NB * NQT * 16 * 128 * 4
                                   + (size_t)S * NB * NQT * 16 * 4);

    hipLaunchKernelGGL(wt_kernel,   dim3(16, 2, 3), dim3(256), 0, stream, Wq, Wk, Wv, Wt);
    hipLaunchKernelGGL(xb_kernel,   dim3(4096),     dim3(256), 0, stream, X, Xb);
    hipLaunchKernelGGL(proj_kernel, dim3(128, 3),   dim3(256), 0, stream, Xb, Wt, Qs, Kb, Vt);
    hipLaunchKernelGGL(attn_kernel, dim3(S * 32 * NB), dim3(256), 0, stream,
                       Qs, Kb, Vt, Zp, Mp, Lp, Out, S, (S == 1) ? 1 : 0);
    if (S > 1)
        hipLaunchKernelGGL(combine_kernel, dim3(NQT, NB), dim3(256), 0, stream,
                           Zp, Mp, Lp, Out, S);
}

// Round 5
// 51.766 us; speedup vs baseline: 2.1681x; 1.1360x over previous
//
#include <hip/hip_runtime.h>
#include <hip/hip_bf16.h>

typedef __bf16 bf16;
typedef __attribute__((ext_vector_type(4))) __bf16 bf16x4;
typedef __attribute__((ext_vector_type(8))) __bf16 bf16x8;
typedef __attribute__((ext_vector_type(4))) float f32x4;

#define D_MODEL 1024
#define DK 128
#define LSEQ 2048
#define NQT 128
#define NB 4
// 1/sqrt(128) * log2(e): softmax runs in exp2 domain end-to-end
#define SCALE2 (0.08838834764831845f * 1.4426950408889634f)

// ---------------------------------------------------------------------------
// Kernel 0: transpose + bf16-convert weights. W[1024][128] f32 -> Wt[3][128][1024]
// ---------------------------------------------------------------------------
__global__ __launch_bounds__(256) void wt_kernel(
    const float* __restrict__ Wq, const float* __restrict__ Wk,
    const float* __restrict__ Wv, bf16* __restrict__ Wt)
{
    __shared__ bf16 tile[64][72];
    const float* W = (blockIdx.z == 0) ? Wq : (blockIdx.z == 1) ? Wk : Wv;
    int k0 = blockIdx.x * 64;
    int n0 = blockIdx.y * 64;
    int t  = threadIdx.x;
    #pragma unroll
    for (int i = 0; i < 16; ++i) {
        int idx = t + i * 256;
        int r = idx >> 6, c = idx & 63;
        tile[c][r] = (bf16)W[(size_t)(k0 + r) * DK + n0 + c];
    }
    __syncthreads();
    bf16* out = Wt + (size_t)blockIdx.z * DK * D_MODEL;
    #pragma unroll
    for (int i = 0; i < 16; ++i) {
        int idx = t + i * 256;
        int rr = idx >> 6, cc = idx & 63;
        out[(size_t)(n0 + rr) * D_MODEL + k0 + cc] = tile[rr][cc];
    }
}

// ---------------------------------------------------------------------------
// Kernel 1: QKV projection GEMM. X f32 [8192][1024] x Wt[mat][128][1024] bf16.
// M-tile 64, BK 64, 4 waves; wave = 64 rows x 32 cols (acc[4][2]).
// Reg-staged double-buffer; f32->bf16 conversion happens reg->LDS.
// Grid (128,3): all 3 mats of M-tile mt land on XCD mt%8 concurrently,
// so the X tile is fetched to L2 once and shared.
// ---------------------------------------------------------------------------
__global__ __launch_bounds__(256) void proj_kernel(
    const float* __restrict__ X, const bf16* __restrict__ Wt,
    bf16* __restrict__ Qs, bf16* __restrict__ Kb, bf16* __restrict__ Vt)
{
    __shared__ bf16 Xs[64][72];
    __shared__ bf16 Ws[128][72];
    int mt = blockIdx.x, mat = blockIdx.y;
    const bf16* W = Wt + (size_t)mat * DK * D_MODEL;
    int t = threadIdx.x;
    int wave = t >> 6, lane = t & 63;
    int lq = lane & 15, g = lane >> 4;
    int row0 = mt * 64;

    f32x4 acc[4][2];
    #pragma unroll
    for (int m = 0; m < 4; ++m)
        #pragma unroll
        for (int n = 0; n < 2; ++n) acc[m][n] = f32x4{0.f, 0.f, 0.f, 0.f};

    f32x4  rxf[4];
    bf16x8 rw[4];
    auto LOADR = [&](int k0) {
        #pragma unroll
        for (int i = 0; i < 4; ++i) {           // X: 64 rows x 16 f32x4 slots
            int u = t + i * 256, r = u >> 4, c4 = u & 15;
            rxf[i] = *reinterpret_cast<const f32x4*>(
                &X[(size_t)(row0 + r) * D_MODEL + k0 + c4 * 4]);
        }
        #pragma unroll
        for (int i = 0; i < 4; ++i) {           // W: 128 rows x 8 bf16x8 slots
            int u = t + i * 256, r = u >> 3, c8 = u & 7;
            rw[i] = *reinterpret_cast<const bf16x8*>(
                &W[(size_t)r * D_MODEL + k0 + c8 * 8]);
        }
    };
    auto STORER = [&]() {
        #pragma unroll
        for (int i = 0; i < 4; ++i) {
            int u = t + i * 256, r = u >> 4, c4 = u & 15;
            bf16x4 h;
            h[0]=(bf16)rxf[i][0]; h[1]=(bf16)rxf[i][1];
            h[2]=(bf16)rxf[i][2]; h[3]=(bf16)rxf[i][3];
            *reinterpret_cast<bf16x4*>(&Xs[r][c4 * 4]) = h;
        }
        #pragma unroll
        for (int i = 0; i < 4; ++i) {
            int u = t + i * 256, r = u >> 3, c8 = u & 7;
            *reinterpret_cast<bf16x8*>(&Ws[r][c8 * 8]) = rw[i];
        }
    };

    LOADR(0);
    for (int ks = 0; ks < 16; ++ks) {
        __syncthreads();
        STORER();
        if (ks + 1 < 16) LOADR((ks + 1) * 64);   // in flight during compute
        __syncthreads();
        #pragma unroll
        for (int kk = 0; kk < 2; ++kk) {
            bf16x8 a[4];
            #pragma unroll
            for (int mr = 0; mr < 4; ++mr)
                a[mr] = *reinterpret_cast<const bf16x8*>(&Xs[mr * 16 + lq][kk * 32 + g * 8]);
            #pragma unroll
            for (int n = 0; n < 2; ++n) {
                bf16x8 bfr = *reinterpret_cast<const bf16x8*>(
                    &Ws[wave * 32 + n * 16 + lq][kk * 32 + g * 8]);
                #pragma unroll
                for (int mr = 0; mr < 4; ++mr)
                    acc[mr][n] = __builtin_amdgcn_mfma_f32_16x16x32_bf16(a[mr], bfr, acc[mr][n], 0, 0, 0);
            }
        }
    }
    #pragma unroll
    for (int mr = 0; mr < 4; ++mr) {
        int orow = row0 + mr * 16 + g * 4;
        #pragma unroll
        for (int n = 0; n < 2; ++n) {
            int col = wave * 32 + n * 16 + lq;
            if (mat == 0) {
                #pragma unroll
                for (int r = 0; r < 4; ++r)
                    Qs[(size_t)(orow + r) * DK + col] = (bf16)(acc[mr][n][r] * SCALE2);
            } else if (mat == 1) {
                #pragma unroll
                for (int r = 0; r < 4; ++r)
                    Kb[(size_t)(orow + r) * DK + col] = (bf16)acc[mr][n][r];
            } else {
                int bb  = orow >> 11;
                int kv0 = orow & 2047;
                bf16x4 h;
                h[0]=(bf16)acc[mr][n][0]; h[1]=(bf16)acc[mr][n][1];
                h[2]=(bf16)acc[mr][n][2]; h[3]=(bf16)acc[mr][n][3];
                *reinterpret_cast<bf16x4*>(
                    &Vt[((size_t)bb * DK + col) * LSEQ + kv0]) = h;
            }
        }
    }
}

// ---------------------------------------------------------------------------
// Kernel 2: split-KV causal flash attention, block-shared K/V LDS staging,
// reg-prefetched one tile ahead (T14), s_setprio around MFMA clusters (T5).
// Block = 4 waves = 64 contiguous q-rows, identical kv range per wave.
// ---------------------------------------------------------------------------
__global__ __launch_bounds__(256, 3) void attn_kernel(
    const bf16* __restrict__ Qs, const bf16* __restrict__ Kb,
    const bf16* __restrict__ Vt, float* __restrict__ Zp,
    float* __restrict__ Mp, float* __restrict__ Lp,
    float* __restrict__ Out, int S, int direct)
{
    __shared__ bf16 Ks[64][136];
    __shared__ bf16 Vs[128][72];
    __shared__ bf16 P[4][16][72];
    int bid = blockIdx.x;
    int b, qblk, s;
    if (S == 4) {
        int xcd = bid & 7, n = bid >> 3;      // n in [0,64)
        b = xcd >> 1;                         // XCD-pinned batch (L2 locality)
        int half = n >> 5, qraw = n & 31;
        qblk = half ? (31 - qraw) : qraw;     // complementary pairing
        s = ((xcd & 1) << 1) | half;
    } else {
        b = bid / (S * 32);
        int rem = bid % (S * 32);
        qblk = rem & 31;
        s = rem >> 5;
    }
    int t = threadIdx.x;
    int wave = t >> 6, lane = t & 63;
    int lq = lane & 15, g = lane >> 4;
    int qw16 = qblk * 4 + wave;
    int qg = qw16 * 16 + lq;

    int nt  = qblk + 1;                  // identical for all 4 waves
    int cpt = (nt + S - 1) / S;
    int t0  = s * cpt;
    int t1  = min(t0 + cpt, nt);

    const bf16* Kbase = Kb + (size_t)b * LSEQ * DK;
    const bf16* Vbase = Vt + (size_t)b * DK * LSEQ;

    const bf16* Qrow = Qs + ((size_t)b * LSEQ + qg) * DK;
    bf16x8 qf[4];
    #pragma unroll
    for (int ks = 0; ks < 4; ++ks)
        qf[ks] = *reinterpret_cast<const bf16x8*>(&Qrow[ks * 32 + g * 8]);

    f32x4 z[8];
    #pragma unroll
    for (int i = 0; i < 8; ++i) z[i] = f32x4{0.f, 0.f, 0.f, 0.f};
    float mrun = -3.0e38f, lrun = 0.f;

    bf16x8 kreg[4], vreg[4];
    auto LOADKV = [&](int kvb) {
        #pragma unroll
        for (int i = 0; i < 4; ++i) {        // K: 64 rows x 16 chunks
            int u = t + i * 256, r = u >> 4, c = u & 15;
            kreg[i] = *reinterpret_cast<const bf16x8*>(
                &Kbase[(size_t)(kvb + r) * DK + c * 8]);
        }
        #pragma unroll
        for (int i = 0; i < 4; ++i) {        // V: 128 rows x 8 chunks
            int u = t + i * 256, d = u >> 3, c = u & 7;
            vreg[i] = *reinterpret_cast<const bf16x8*>(
                &Vbase[(size_t)d * LSEQ + kvb + c * 8]);
        }
    };
    auto STOREKV = [&]() {
        #pragma unroll
        for (int i = 0; i < 4; ++i) {
            int u = t + i * 256, r = u >> 4, c = u & 15;
            *reinterpret_cast<bf16x8*>(&Ks[r][c * 8]) = kreg[i];
        }
        #pragma unroll
        for (int i = 0; i < 4; ++i) {
            int u = t + i * 256, d = u >> 3, c = u & 7;
            *reinterpret_cast<bf16x8*>(&Vs[d][c * 8]) = vreg[i];
        }
    };

    if (t0 < t1) {                       // block-uniform
        LOADKV(t0 * 64);
        for (int ti = t0; ti < t1; ++ti) {
            int kvb = ti * 64;
            __syncthreads();             // prev tile's readers done
            STOREKV();
            if (ti + 1 < t1) LOADKV((ti + 1) * 64);   // hide under compute
            __syncthreads();             // LDS tile visible

            f32x4 sc[4];
            #pragma unroll
            for (int jj = 0; jj < 4; ++jj) sc[jj] = f32x4{0.f, 0.f, 0.f, 0.f};
            __builtin_amdgcn_s_setprio(1);
            #pragma unroll
            for (int jj = 0; jj < 4; ++jj)
                #pragma unroll
                for (int ks = 0; ks < 4; ++ks) {
                    bf16x8 a = *reinterpret_cast<const bf16x8*>(
                        &Ks[jj * 16 + lq][ks * 32 + g * 8]);
                    sc[jj] = __builtin_amdgcn_mfma_f32_16x16x32_bf16(a, qf[ks], sc[jj], 0, 0, 0);
                }
            __builtin_amdgcn_s_setprio(0);

            float sv[16];
            if (ti == nt - 1) {          // only the diagonal tile masks
                #pragma unroll
                for (int jj = 0; jj < 4; ++jj)
                    #pragma unroll
                    for (int r = 0; r < 4; ++r) {
                        int kv0 = kvb + jj * 16 + g * 4 + r;
                        sv[jj * 4 + r] = (kv0 <= qg) ? sc[jj][r] : -3.0e38f;
                    }
            } else {
                #pragma unroll
                for (int jj = 0; jj < 4; ++jj)
                    #pragma unroll
                    for (int r = 0; r < 4; ++r) sv[jj * 4 + r] = sc[jj][r];
            }
            float mt = sv[0];
            #pragma unroll
            for (int i = 1; i < 16; ++i) mt = fmaxf(mt, sv[i]);
            mt = fmaxf(mt, __shfl_xor(mt, 16));
            mt = fmaxf(mt, __shfl_xor(mt, 32));
            if (!__all(mt <= mrun)) {
                float mnew  = fmaxf(mrun, mt);
                float alpha = exp2f(mrun - mnew);
                lrun *= alpha;
                #pragma unroll
                for (int i = 0; i < 8; ++i) {
                    z[i][0] *= alpha; z[i][1] *= alpha; z[i][2] *= alpha; z[i][3] *= alpha;
                }
                mrun = mnew;
            }
            float psum = 0.f;
            #pragma unroll
            for (int jj = 0; jj < 4; ++jj) {
                bf16x4 pb;
                #pragma unroll
                for (int r = 0; r < 4; ++r) {
                    float e = exp2f(sv[jj * 4 + r] - mrun);
                    psum += e;
                    pb[r] = (bf16)e;
                }
                *reinterpret_cast<bf16x4*>(&P[wave][lq][jj * 16 + g * 4]) = pb;
            }
            psum += __shfl_xor(psum, 16);
            psum += __shfl_xor(psum, 32);
            lrun += psum;
            __builtin_amdgcn_s_setprio(1);
            #pragma unroll
            for (int sl = 0; sl < 2; ++sl) {
                bf16x8 pf = *reinterpret_cast<const bf16x8*>(&P[wave][lq][sl * 32 + g * 8]);
                #pragma unroll
                for (int dt = 0; dt < 8; ++dt) {
                    bf16x8 av = *reinterpret_cast<const bf16x8*>(
                        &Vs[dt * 16 + lq][sl * 32 + g * 8]);
                    z[dt] = __builtin_amdgcn_mfma_f32_16x16x32_bf16(av, pf, z[dt], 0, 0, 0);
                }
            }
            __builtin_amdgcn_s_setprio(0);
        }
    }

    if (direct) {
        float inv = 1.f / lrun;
        float* orow = Out + ((size_t)b * LSEQ + qg) * DK;
        #pragma unroll
        for (int dt = 0; dt < 8; ++dt) {
            f32x4 v;
            v[0]=z[dt][0]*inv; v[1]=z[dt][1]*inv; v[2]=z[dt][2]*inv; v[3]=z[dt][3]*inv;
            *reinterpret_cast<f32x4*>(&orow[dt * 16 + g * 4]) = v;
        }
    } else {
        size_t T = ((size_t)(b * NQT + qw16) * S + s);
        float* zp = Zp + T * (16 * 128);
        #pragma unroll
        for (int dt = 0; dt < 8; ++dt)
            *reinterpret_cast<f32x4*>(&zp[lq * 128 + dt * 16 + g * 4]) = z[dt];
        if (g == 0) {
            Mp[T * 16 + lq] = mrun;
            Lp[T * 16 + lq] = lrun;
        }
    }
}

// ---------------------------------------------------------------------------
// Kernel 3: merge split-KV partials. One block per (qt16, b), 256 threads.
// ---------------------------------------------------------------------------
__global__ __launch_bounds__(256) void combine_kernel(
    const float* __restrict__ Zp, const float* __restrict__ Mp,
    const float* __restrict__ Lp, float* __restrict__ Out, int S)
{
    int qt = blockIdx.x, b = blockIdx.y;
    int t  = threadIdx.x;
    int r  = t >> 4;
    int d0 = (t & 15) * 8;
    size_t Tbase = (size_t)(b * NQT + qt) * S;

    float m = -3.0e38f;
    for (int s = 0; s < S; ++s)
        m = fmaxf(m, Mp[(Tbase + s) * 16 + r]);

    float L = 0.f;
    f32x4 a0 = {0.f,0.f,0.f,0.f}, a1 = {0.f,0.f,0.f,0.f};
    for (int s = 0; s < S; ++s) {
        float w = exp2f(Mp[(Tbase + s) * 16 + r] - m);
        L += w * Lp[(Tbase + s) * 16 + r];
        const float* zp = Zp + (Tbase + s) * (16 * 128) + r * 128 + d0;
        f32x4 v0 = *reinterpret_cast<const f32x4*>(&zp[0]);
        f32x4 v1 = *reinterpret_cast<const f32x4*>(&zp[4]);
        a0[0]+=w*v0[0]; a0[1]+=w*v0[1]; a0[2]+=w*v0[2]; a0[3]+=w*v0[3];
        a1[0]+=w*v1[0]; a1[1]+=w*v1[1]; a1[2]+=w*v1[2]; a1[3]+=w*v1[3];
    }
    float inv = 1.f / L;
    float* orow = Out + ((size_t)b * LSEQ + qt * 16 + r) * DK + d0;
    f32x4 o0, o1;
    o0[0]=a0[0]*inv; o0[1]=a0[1]*inv; o0[2]=a0[2]*inv; o0[3]=a0[3]*inv;
    o1[0]=a1[0]*inv; o1[1]=a1[1]*inv; o1[2]=a1[2]*inv; o1[3]=a1[3]*inv;
    *reinterpret_cast<f32x4*>(&orow[0]) = o0;
    *reinterpret_cast<f32x4*>(&orow[4]) = o1;
}

// ---------------------------------------------------------------------------
extern "C" void kernel_launch(void* const* d_in, const int* in_sizes, int n_in,
                              void* d_out, int out_size, void* d_ws, size_t ws_size,
                              hipStream_t stream)
{
    const float* X  = (const float*)d_in[0];
    const float* Wq = (const float*)d_in[1];
    const float* Wk = (const float*)d_in[2];
    const float* Wv = (const float*)d_in[3];
    float* Out = (float*)d_out;

    char* ws = (char*)d_ws;
    // layout: Wt @0 (768KB) ; Qs @1MB ; Kb @3MB ; Vt @5MB ; partials @7MB
    bf16* Wt = (bf16*)(ws);
    bf16* Qs = (bf16*)(ws + ((size_t)1 << 20));
    bf16* Kb = (bf16*)(ws + ((size_t)3 << 20));
    bf16* Vt = (bf16*)(ws + ((size_t)5 << 20));
    size_t base = (size_t)7 << 20;

    auto need = [](int S) -> size_t {
        return ((size_t)7 << 20) + (size_t)S * ((size_t)NB * NQT * 16 * 128 * 4)
                                 + (size_t)S * 2 * ((size_t)NB * NQT * 16 * 4);
    };
    int S = 1;
    if      (ws_size >= need(4)) S = 4;
    else if (ws_size >= need(2)) S = 2;

    float* Zp = (float*)(ws + base);
    float* Mp = (float*)(ws + base + (size_t)S * NB * NQT * 16 * 128 * 4);
    float* Lp = (float*)(ws + base + (size_t)S * NB * NQT * 16 * 128 * 4
                                   + (size_t)S * NB * NQT * 16 * 4);

    hipLaunchKernelGGL(wt_kernel,   dim3(16, 2, 3), dim3(256), 0, stream, Wq, Wk, Wv, Wt);
    hipLaunchKernelGGL(proj_kernel, dim3(128, 3),   dim3(256), 0, stream, X, Wt, Qs, Kb, Vt);
    hipLaunchKernelGGL(attn_kernel, dim3(S * 32 * NB), dim3(256), 0, stream,
                       Qs, Kb, Vt, Zp, Mp, Lp, Out, S, (S == 1) ? 1 : 0);
    if (S > 1)
        hipLaunchKernelGGL(combine_kernel, dim3(NQT, NB), dim3(256), 0, stream,
                           Zp, Mp, Lp, Out, S);
}